// Round 12
// baseline (3427.131 us; speedup 1.0000x reference)
//
#include <hip/hip_runtime.h>
#include <hip/hip_bf16.h>
#include <hip/hip_fp16.h>

using half_t = _Float16;
typedef __attribute__((ext_vector_type(8))) _Float16 f16x8;  // 8 fp16 = 4 VGPRs (MFMA frag)
typedef __attribute__((ext_vector_type(4))) _Float16 f16x4;
typedef __attribute__((ext_vector_type(4))) float f32x4;

#define LN_EPS 1e-5f

// async global->LDS, 16B per lane. gptr is PER-LANE, ldsbase is wave-uniform;
// HW writes ldsbase + lane*16.  [m97/m173 pattern]
__device__ inline void gll16(const void* g, void* ldsbase) {
    __builtin_amdgcn_global_load_lds(
        (const __attribute__((address_space(1))) void*)g,
        (__attribute__((address_space(3))) void*)ldsbase, 16, 0, 0);
}

// ---------------------------------------------------------------------------
// Wave-scope LN-LSTM cell, fused-pre variant: pre (bias included) is ONE
// buffer [512][4096]. One 64-lane wave owns one batch row (16 elems/lane).
// ---------------------------------------------------------------------------
__device__ inline void cell_wave1(
    int b, int l, const half_t* __restrict__ pre,
    float* __restrict__ cst, half_t* __restrict__ hs,
    float* __restrict__ hf, bool final_step)
{
    float cn[16], og[16];
    float s = 0.f;
    #pragma unroll
    for (int j = 0; j < 4; ++j) {
        const int e = j*256 + l*4;
        const size_t pbase = (size_t)b*4096 + e;
        f16x4 a0 = *(const f16x4*)&pre[pbase];
        f16x4 a1 = *(const f16x4*)&pre[pbase + 1024];
        f16x4 a2 = *(const f16x4*)&pre[pbase + 2048];
        f16x4 a3 = *(const f16x4*)&pre[pbase + 3072];
        float4 c4 = *(const float4*)&cst[(size_t)b*1024 + e];
        const float* cp = (const float*)&c4;
        #pragma unroll
        for (int k = 0; k < 4; ++k) {
            float ig = 1.f / (1.f + expf(-(float)a0[k]));
            float fg = 1.f / (1.f + expf(-(float)a1[k]));
            og[j*4+k] = 1.f / (1.f + expf(-(float)a2[k]));
            float ct = tanhf((float)a3[k]);
            float cv = fg * cp[k] + ig * ct;
            cn[j*4+k] = cv; s += cv;
        }
    }
    #pragma unroll
    for (int off = 1; off < 64; off <<= 1) s += __shfl_xor(s, off, 64);
    const float mu = s * (1.f/1024.f);
    float vs = 0.f;
    #pragma unroll
    for (int i = 0; i < 16; ++i) { float d = cn[i] - mu; vs += d*d; }
    #pragma unroll
    for (int off = 1; off < 64; off <<= 1) vs += __shfl_xor(vs, off, 64);
    const float rs = rsqrtf(vs * (1.f/1024.f) + LN_EPS);
    #pragma unroll
    for (int j = 0; j < 4; ++j) {
        const int e = j*256 + l*4;
        f16x4 h4; float4 hf4, c4;
        float* hfp = (float*)&hf4; float* cp = (float*)&c4;
        #pragma unroll
        for (int k = 0; k < 4; ++k) {
            float cv = (cn[j*4+k] - mu) * rs;
            float hv = og[j*4+k] * tanhf(cv);
            h4[k] = (half_t)hv;
            hfp[k] = hv; cp[k] = cv;
        }
        *(float4*)&cst[(size_t)b*1024 + e] = c4;
        *(f16x4*)&hs[(size_t)b*1024 + e]  = h4;
        if (final_step) *(float4*)&hf[(size_t)b*1024 + e] = hf4;
    }
}

// cells(t): WGs 0..127 -> cell1(t) from pre1; 128..255 -> cell2(t-1) from pre2.
__global__ __launch_bounds__(256) void cells_kernel(
    const half_t* __restrict__ pre1, const half_t* __restrict__ pre2,
    float* __restrict__ c0, float* __restrict__ c1,
    half_t* __restrict__ h0s, half_t* __restrict__ h1s,
    float* __restrict__ h0f, float* __restrict__ h1f, int st)
{
    const int wg = blockIdx.x, l = threadIdx.x & 63, w = threadIdx.x >> 6;
    if (wg < 128) {
        cell_wave1(wg*4 + w, l, pre1, c0, h0s, h0f, st == 63);
    } else if (st > 0) {
        cell_wave1((wg-128)*4 + w, l, pre2, c1, h1s, h1f, false);
    }
}

// final cell2(63)
__global__ __launch_bounds__(256) void cells_final(
    const half_t* __restrict__ pre2,
    float* __restrict__ c1, half_t* __restrict__ h1s, float* __restrict__ h1f)
{
    cell_wave1(blockIdx.x*4 + (threadIdx.x >> 6), threadIdx.x & 63,
               pre2, c1, h1s, h1f, true);
}

// ---------------------------------------------------------------------------
// Fused step GEMM: K=2048 two-pointer A, bias in epilogue. 512 WGs:
//   wg = ylo + 8*(x + 4*(z + 2*yhi)); tile 128(M) x 64(N), 32 K-tiles.
//   z0: pre2(t)   = [h0(t) | h1(t-1)] @ wcat2^T + b2   (skip st<0)
//   z1: pre1(t+1) = [X(t+1)| h0(t) ]  @ wcat1^T + b1   (skip st==63)
// A-half select per K-tile (kt<16 -> part0, else part1). Weights wcat
// [4096][2048]; y%8 == dispatch%8 -> panels XCD-pinned (4 MB/XCD).
// 2-phase pipeline, XOR-swizzled global_load_lds staging (both sides).
// ---------------------------------------------------------------------------
__global__ __launch_bounds__(256, 2) void step_gemm_f(
    const half_t* __restrict__ Xnext, size_t ldx,
    const half_t* __restrict__ wcat1, const half_t* __restrict__ wcat2,
    const float* __restrict__ b1, const float* __restrict__ b2,
    half_t* __restrict__ pre1, half_t* __restrict__ pre2,
    const half_t* __restrict__ h0s, const half_t* __restrict__ h1s, int st)
{
    __shared__ __align__(16) unsigned char sA[2][16384];
    __shared__ __align__(16) unsigned char sB[2][8192];

    const int wg = blockIdx.x;
    const int ylo = wg & 7;
    int r = wg >> 3;
    const int x = r & 3; r >>= 2;
    const int z = r & 1; r >>= 1;
    const int y = ylo + 8 * r;                    // 0..63

    if (z == 0 && st < 0) return;
    if (z == 1 && st == 63) return;

    const half_t *A0, *A1, *B; size_t lda0, lda1; const float* bias; half_t* C;
    if (z == 0) { A0 = h0s;   lda0 = 1024; A1 = h1s; lda1 = 1024; B = wcat2; bias = b2; C = pre2; }
    else        { A0 = Xnext; lda0 = ldx;  A1 = h0s; lda1 = 1024; B = wcat1; bias = b1; C = pre1; }

    const int t = threadIdx.x, l = t & 63, w = t >> 6;
    const int wr = (w >> 1) * 64, wc = (w & 1) * 32;
    const int rowbase = x * 128, colbase = y * 64;

    // staging geometry: A slots s=(w*4+i)*64+l (rows 0..127); B slots (w*2+i)*64+l (rows 0..63)
    int srA[4], scA[4], srB[2], scB[2];
    #pragma unroll
    for (int i = 0; i < 4; ++i) {
        int s = (w*4 + i)*64 + l;
        srA[i] = s >> 3; scA[i] = ((s & 7) ^ (srA[i] & 7)) * 8;
    }
    #pragma unroll
    for (int i = 0; i < 2; ++i) {
        int s = (w*2 + i)*64 + l;
        srB[i] = s >> 3; scB[i] = ((s & 7) ^ (srB[i] & 7)) * 8;
    }

    f32x4 acc[4][2];
    #pragma unroll
    for (int m = 0; m < 4; ++m)
        #pragma unroll
        for (int n = 0; n < 2; ++n) acc[m][n] = (f32x4)(0.f);

    auto stage = [&](int kt, int buf) {
        const half_t* Ap; size_t la; int ko;
        if (kt < 16) { Ap = A0; la = lda0; ko = kt * 64; }
        else         { Ap = A1; la = lda1; ko = (kt - 16) * 64; }
        #pragma unroll
        for (int i = 0; i < 4; ++i)
            gll16(Ap + (size_t)(rowbase+srA[i])*la + ko + scA[i], &sA[buf][(w*4+i)*1024]);
        const int kb = kt * 64;
        #pragma unroll
        for (int i = 0; i < 2; ++i)
            gll16(B + (size_t)(colbase+srB[i])*2048 + kb + scB[i], &sB[buf][(w*2+i)*1024]);
    };

    stage(0, 0);
    for (int kt = 0; kt < 32; ++kt) {
        const int buf = kt & 1;
        __syncthreads();                 // vmcnt(0): buf ready; WAR-safe for buf^1
        if (kt + 1 < 32) stage(kt + 1, buf ^ 1);
        #pragma unroll
        for (int kk = 0; kk < 2; ++kk) {
            const int chunk = kk*4 + (l >> 4);
            f16x8 bfr[2];
            #pragma unroll
            for (int n = 0; n < 2; ++n) {
                int rowb = wc + n*16 + (l & 15);
                bfr[n] = *(const f16x8*)&sB[buf][rowb*128 + ((chunk ^ (rowb & 7)) << 4)];
            }
            #pragma unroll
            for (int m = 0; m < 4; ++m) {
                int rowa = wr + m*16 + (l & 15);
                f16x8 af = *(const f16x8*)&sA[buf][rowa*128 + ((chunk ^ (rowa & 7)) << 4)];
                #pragma unroll
                for (int n = 0; n < 2; ++n)
                    acc[m][n] = __builtin_amdgcn_mfma_f32_16x16x32_f16(af, bfr[n], acc[m][n], 0, 0, 0);
            }
        }
    }

    // epilogue: C/D layout col = lane&15, row = (lane>>4)*4 + reg  [m89/m91]
    #pragma unroll
    for (int m = 0; m < 4; ++m) {
        int row0 = rowbase + wr + m*16 + (l >> 4)*4;
        #pragma unroll
        for (int n = 0; n < 2; ++n) {
            int col = colbase + wc + n*16 + (l & 15);
            float bv = bias[col];
            #pragma unroll
            for (int r2 = 0; r2 < 4; ++r2)
                C[(size_t)(row0+r2)*4096 + col] = (half_t)(acc[m][n][r2] + bv);
        }
    }
}

struct GArgs {
    const half_t* A; const half_t* B; const float* bias; void* C;
    int lda, ldb, K, ldc, outhalf;
};

// ---------------------------------------------------------------------------
// Multi-set fp16 GEMM (fc1 / fc2 / fallback): up to 3 independent C=A*B^T.
// ---------------------------------------------------------------------------
__global__ __launch_bounds__(256) void gemm_ms(GArgs g0, GArgs g1, GArgs g2,
                                               int gx, int gz)
{
    const int d   = blockIdx.x;
    const int ylo = d & 7;
    int r   = d >> 3;
    const int x  = r % gx;  r /= gx;
    const int z  = r % gz;
    const int y  = ylo + 8 * (r / gz);

    const GArgs g = (z == 0) ? g0 : (z == 1 ? g1 : g2);

    __shared__ __align__(16) unsigned char sA[2][16384];
    __shared__ __align__(16) unsigned char sB[2][16384];

    const int t  = threadIdx.x;
    const int l  = t & 63;
    const int w  = t >> 6;
    const int wr = (w >> 1) * 64;
    const int wc = (w & 1)  * 64;
    const int rowbase = x * 128;
    const int colbase = y * 128;

    f32x4 acc[4][4];
    #pragma unroll
    for (int m = 0; m < 4; ++m)
        #pragma unroll
        for (int n = 0; n < 4; ++n) acc[m][n] = (f32x4)(0.f);

    int srow[4], sch[4];
    #pragma unroll
    for (int i = 0; i < 4; ++i) {
        int s = (w*4 + i)*64 + l;
        srow[i] = s >> 3;
        sch[i]  = ((s & 7) ^ (srow[i] & 7)) * 8;
    }

    const int nkt = g.K >> 6;

    auto stage = [&](int kt, int buf) {
        const int ko = kt * 64;
        #pragma unroll
        for (int i = 0; i < 4; ++i) {
            gll16(g.A + (size_t)(rowbase+srow[i])*g.lda + ko + sch[i], &sA[buf][(w*4+i)*1024]);
            gll16(g.B + (size_t)(colbase+srow[i])*g.ldb + ko + sch[i], &sB[buf][(w*4+i)*1024]);
        }
    };

    stage(0, 0);
    for (int kt = 0; kt < nkt; ++kt) {
        const int buf = kt & 1;
        __syncthreads();
        if (kt + 1 < nkt) stage(kt + 1, buf ^ 1);
        #pragma unroll
        for (int kk = 0; kk < 2; ++kk) {
            const int chunk = kk*4 + (l >> 4);
            f16x8 bfr[4];
            #pragma unroll
            for (int n = 0; n < 4; ++n) {
                int rowb = wc + n*16 + (l & 15);
                bfr[n] = *(const f16x8*)&sB[buf][rowb*128 + ((chunk ^ (rowb & 7)) << 4)];
            }
            #pragma unroll
            for (int m = 0; m < 4; ++m) {
                int rowa = wr + m*16 + (l & 15);
                f16x8 af = *(const f16x8*)&sA[buf][rowa*128 + ((chunk ^ (rowa & 7)) << 4)];
                #pragma unroll
                for (int n = 0; n < 4; ++n)
                    acc[m][n] = __builtin_amdgcn_mfma_f32_16x16x32_f16(af, bfr[n], acc[m][n], 0, 0, 0);
            }
        }
    }

    #pragma unroll
    for (int m = 0; m < 4; ++m) {
        int row0 = rowbase + wr + m*16 + (l >> 4)*4;
        #pragma unroll
        for (int n = 0; n < 4; ++n) {
            int col = colbase + wc + n*16 + (l & 15);
            float bv = g.bias ? g.bias[col] : 0.f;
            #pragma unroll
            for (int r2 = 0; r2 < 4; ++r2) {
                float v = acc[m][n][r2] + bv;
                if (g.outhalf) ((half_t*)g.C)[(size_t)(row0+r2)*g.ldc + col] = (half_t)v;
                else           ((float*)g.C)[(size_t)(row0+r2)*g.ldc + col] = v;
            }
        }
    }
}

// ---------------------------------------------------------------------------
// wx (fp32 [4096][1024]) -> wcat cols 0..1023 (half, row stride 2048)
__global__ __launch_bounds__(256) void cvt_cat(
    const float* __restrict__ in, half_t* __restrict__ out, int n8)
{
    int i = blockIdx.x * 256 + threadIdx.x;
    if (i >= n8) return;
    int p = i * 8, row = p >> 10, col = p & 1023;
    float4 lo = ((const float4*)in)[2*i];
    float4 hi = ((const float4*)in)[2*i + 1];
    union { uint4 v; half_t h[8]; } r;
    r.h[0]=(half_t)lo.x; r.h[1]=(half_t)lo.y; r.h[2]=(half_t)lo.z; r.h[3]=(half_t)lo.w;
    r.h[4]=(half_t)hi.x; r.h[5]=(half_t)hi.y; r.h[6]=(half_t)hi.z; r.h[7]=(half_t)hi.w;
    *(uint4*)&out[(size_t)row*2048 + col] = r.v;
}

// wh[g] (K x N fp32) -> wcat cols 1024..2047 transposed (half, row stride 2048)
__global__ __launch_bounds__(256) void transpose_cat(
    const float* __restrict__ wh1, const float* __restrict__ wh2,
    half_t* __restrict__ wcat1, half_t* __restrict__ wcat2)
{
    __shared__ float tile[64][65];
    const int z = blockIdx.z;
    const float* src = (z < 4 ? wh1 : wh2) + (size_t)(z & 3) * 1024 * 1024;
    half_t*      dst = (z < 4 ? wcat1 : wcat2);
    const int kb = blockIdx.x * 64, nb = blockIdx.y * 64;
    const int t = threadIdx.x;
    #pragma unroll
    for (int i = 0; i < 16; ++i) {
        int idx = t + i*256, r = idx >> 6, c = idx & 63;
        tile[r][c] = src[(size_t)(kb + r)*1024 + nb + c];
    }
    __syncthreads();
    #pragma unroll
    for (int i = 0; i < 16; ++i) {
        int idx = t + i*256, r = idx >> 6, c = idx & 63;
        dst[(size_t)((z & 3)*1024 + nb + r)*2048 + 1024 + kb + c] = (half_t)tile[c][r];
    }
}

__global__ __launch_bounds__(256) void cvt_f32_f16(
    const float* __restrict__ in, half_t* __restrict__ out, int n8)
{
    int i = blockIdx.x * 256 + threadIdx.x;
    if (i >= n8) return;
    float4 lo = ((const float4*)in)[2*i];
    float4 hi = ((const float4*)in)[2*i + 1];
    union { uint4 v; half_t h[8]; } r;
    r.h[0]=(half_t)lo.x; r.h[1]=(half_t)lo.y; r.h[2]=(half_t)lo.z; r.h[3]=(half_t)lo.w;
    r.h[4]=(half_t)hi.x; r.h[5]=(half_t)hi.y; r.h[6]=(half_t)hi.z; r.h[7]=(half_t)hi.w;
    ((uint4*)out)[i] = r.v;
}

__global__ __launch_bounds__(256) void pack_out(
    const float* __restrict__ h0, const float* __restrict__ h1,
    const float* __restrict__ c0, const float* __restrict__ c1, float* __restrict__ out)
{
    const int NSZ = 512 * 1024;
    int i = blockIdx.x * 256 + threadIdx.x;
    out[NSZ     + i] = h0[i];
    out[2*NSZ   + i] = h1[i];
    out[3*NSZ   + i] = c0[i];
    out[4*NSZ   + i] = c1[i];
}

extern "C" void kernel_launch(void* const* d_in, const int* in_sizes, int n_in,
                              void* d_out, int out_size, void* d_ws, size_t ws_size,
                              hipStream_t stream)
{
    const float* obs   = (const float*)d_in[0];
    const float* fc1_w = (const float*)d_in[1];
    const float* fc1_b = (const float*)d_in[2];
    const float* wx1   = (const float*)d_in[3];
    const float* wh1   = (const float*)d_in[4];
    const float* b1    = (const float*)d_in[5];
    const float* wx2   = (const float*)d_in[6];
    const float* wh2   = (const float*)d_in[7];
    const float* b2    = (const float*)d_in[8];
    const float* fc2_w = (const float*)d_in[9];
    const float* fc2_b = (const float*)d_in[10];
    float* out = (float*)d_out;

    char* ws = (char*)d_ws;
    size_t off = 0;
    auto carve = [&](size_t bytes) -> char* {
        char* p = ws + off; off += (bytes + 255) & ~(size_t)255; return p;
    };
    half_t* obs16 = (half_t*)carve((size_t)512*64*512*2);   // 33.6 MB
    half_t* wcat1 = (half_t*)carve((size_t)4096*2048*2);    // 16.8 MB
    half_t* wcat2 = (half_t*)carve((size_t)4096*2048*2);    // 16.8 MB
    half_t* fc1c  = (half_t*)carve((size_t)1024*512*2);
    half_t* fc2c  = (half_t*)carve((size_t)1024*1024*2);
    half_t* pre1  = (half_t*)carve((size_t)512*4096*2);     //  4.2 MB
    half_t* pre2  = (half_t*)carve((size_t)512*4096*2);     //  4.2 MB
    half_t* h0s   = (half_t*)carve((size_t)512*1024*2);
    half_t* h1s   = (half_t*)carve((size_t)512*1024*2);
    float*  h0f   = (float*) carve((size_t)512*1024*4);
    float*  h1f   = (float*) carve((size_t)512*1024*4);
    float*  c0    = (float*) carve((size_t)512*1024*4);
    float*  c1    = (float*) carve((size_t)512*1024*4);
    half_t* X0a   = (half_t*)carve((size_t)512*1024*2);     // fallback X(t) parity
    half_t* X0b   = (half_t*)carve((size_t)512*1024*2);

    const size_t X_bytes = (size_t)512*64*1024*2;           // 67 MB
    bool modeB = (off + X_bytes) <= ws_size;
    half_t* X = (half_t*)carve(modeB ? X_bytes : 256);

    hipMemsetAsync(h0s, 0, (size_t)512*1024*2, stream);     // h0(-1)=0 (read by st=-1 gemm)
    hipMemsetAsync(h1s, 0, (size_t)512*1024*2, stream);     // h1(-1)=0
    hipMemsetAsync(c0,  0, (size_t)512*1024*4, stream);
    hipMemsetAsync(c1,  0, (size_t)512*1024*4, stream);

    // one-time conversions / weight concat builds
    cvt_f32_f16<<<8192, 256, 0, stream>>>(obs,   obs16, 512*64*512/8);
    cvt_cat<<<2048, 256, 0, stream>>>(wx1, wcat1, 4*1024*1024/8);
    cvt_cat<<<2048, 256, 0, stream>>>(wx2, wcat2, 4*1024*1024/8);
    transpose_cat<<<dim3(16,16,8), 256, 0, stream>>>(wh1, wh2, wcat1, wcat2);
    cvt_f32_f16<<<256,  256, 0, stream>>>(fc1_w, fc1c,  1024*512/8);
    cvt_f32_f16<<<512,  256, 0, stream>>>(fc2_w, fc2c,  1024*1024/8);

    GArgs Z{};
    auto ga = [](const half_t* A, int lda, const half_t* B, int ldb, int K,
                 const float* bias, void* C, int ldc, int outhalf) {
        GArgs g; g.A=A; g.B=B; g.bias=bias; g.C=C;
        g.lda=lda; g.ldb=ldb; g.K=K; g.ldc=ldc; g.outhalf=outhalf; return g;
    };

    if (modeB) {
        // X = obs @ fc1^T + b : M=32768, N=1024, K=512
        gemm_ms<<<256*8, 256, 0, stream>>>(
            ga(obs16, 512, fc1c, 512, 512, fc1_b, X, 1024, 1), Z, Z, 256, 1);
        // pre1(0) = [X(0) | 0] @ wcat1^T + b1   (st=-1: only z1 active)
        step_gemm_f<<<512, 256, 0, stream>>>(
            X, 65536, wcat1, wcat2, b1, b2, pre1, pre2, h0s, h1s, -1);

        for (int st = 0; st < 64; ++st) {
            cells_kernel<<<256, 256, 0, stream>>>(
                pre1, pre2, c0, c1, h0s, h1s, h0f, h1f, st);
            step_gemm_f<<<512, 256, 0, stream>>>(
                X + (size_t)((st + 1 < 64 ? st + 1 : 63))*1024, 65536,
                wcat1, wcat2, b1, b2, pre1, pre2, h0s, h1s, st);
        }
        cells_final<<<128, 256, 0, stream>>>(pre2, c1, h1s, h1f);
    } else {
        // fallback: per-step fc1 into parity X0 buffers
        gemm_ms<<<4*8, 256, 0, stream>>>(
            ga(obs16, 64*512, fc1c, 512, 512, fc1_b, X0a, 1024, 1), Z, Z, 4, 1);
        step_gemm_f<<<512, 256, 0, stream>>>(
            X0a, 1024, wcat1, wcat2, b1, b2, pre1, pre2, h0s, h1s, -1);
        for (int st = 0; st < 64; ++st) {
            cells_kernel<<<256, 256, 0, stream>>>(
                pre1, pre2, c0, c1, h0s, h1s, h0f, h1f, st);
            half_t* Xn = (st & 1) ? X0a : X0b;   // holds X(st+1)
            if (st < 63)
                gemm_ms<<<4*8, 256, 0, stream>>>(
                    ga(obs16 + (size_t)(st+1)*512, 64*512, fc1c, 512, 512, fc1_b, Xn, 1024, 1),
                    Z, Z, 4, 1);
            step_gemm_f<<<512, 256, 0, stream>>>(
                Xn, 1024, wcat1, wcat2, b1, b2, pre1, pre2, h0s, h1s, st);
        }
        cells_final<<<128, 256, 0, stream>>>(pre2, c1, h1s, h1f);
    }

    // fc2: logit = h1 @ fc2_w^T + fc2_b -> d_out[0 : 512*1024) fp32
    gemm_ms<<<4*8, 256, 0, stream>>>(
        ga(h1s, 1024, fc2c, 1024, 1024, fc2_b, out, 1024, 0), Z, Z, 4, 1);
    pack_out<<<2048, 256, 0, stream>>>(h0f, h1f, c0, c1, out);
}

// Round 13
// 2388.544 us; speedup vs baseline: 1.4348x; 1.4348x over previous
//
#include <hip/hip_runtime.h>
#include <hip/hip_bf16.h>
#include <hip/hip_fp16.h>

using half_t = _Float16;
typedef __attribute__((ext_vector_type(8))) _Float16 f16x8;  // 8 fp16 = 4 VGPRs (MFMA frag)
typedef __attribute__((ext_vector_type(4))) _Float16 f16x4;
typedef __attribute__((ext_vector_type(4))) float f32x4;

#define LN_EPS 1e-5f

// async global->LDS, 16B per lane. gptr is PER-LANE, ldsbase is wave-uniform;
// HW writes ldsbase + lane*16.  [m97/m173 pattern]
__device__ inline void gll16(const void* g, void* ldsbase) {
    __builtin_amdgcn_global_load_lds(
        (const __attribute__((address_space(1))) void*)g,
        (__attribute__((address_space(3))) void*)ldsbase, 16, 0, 0);
}

// ---------------------------------------------------------------------------
// Block-per-row LN-LSTM cell (R5-proven shape): 256 thr, 4 contiguous elems
// per thread, LDS block reduce. 4 WG/CU occupancy.
// ---------------------------------------------------------------------------
__device__ inline float block_sum(float v, float* sred) {
    #pragma unroll
    for (int off = 32; off; off >>= 1) v += __shfl_down(v, off, 64);
    __syncthreads();
    if ((threadIdx.x & 63) == 0) sred[threadIdx.x >> 6] = v;
    __syncthreads();
    return sred[0] + sred[1] + sred[2] + sred[3];
}

__device__ inline void cell_block(
    int b, const half_t* __restrict__ preA, const half_t* __restrict__ preB,
    const float* __restrict__ bias,
    float* __restrict__ cst, half_t* __restrict__ hs,
    float* __restrict__ hf, bool final_step)
{
    __shared__ float sred[4];
    const int t = threadIdx.x;
    const int hi = t * 4;
    const size_t pb = (size_t)b * 4096 + hi;
    const size_t cb = (size_t)b * 1024 + hi;

    float pre[4][4];
    #pragma unroll
    for (int g = 0; g < 4; ++g) {
        f16x4 a4 = *(const f16x4*)&preA[pb + g*1024];
        f16x4 v4 = *(const f16x4*)&preB[pb + g*1024];
        float4 bs = *(const float4*)&bias[g*1024 + hi];
        pre[g][0] = (float)a4[0] + (float)v4[0] + bs.x;
        pre[g][1] = (float)a4[1] + (float)v4[1] + bs.y;
        pre[g][2] = (float)a4[2] + (float)v4[2] + bs.z;
        pre[g][3] = (float)a4[3] + (float)v4[3] + bs.w;
    }
    float4 c4 = *(const float4*)&cst[cb];
    float co[4] = {c4.x, c4.y, c4.z, c4.w};

    float cn[4], og[4], s = 0.f;
    #pragma unroll
    for (int j = 0; j < 4; ++j) {
        float ig = 1.f / (1.f + expf(-pre[0][j]));
        float fg = 1.f / (1.f + expf(-pre[1][j]));
        og[j]    = 1.f / (1.f + expf(-pre[2][j]));
        float ct = tanhf(pre[3][j]);
        cn[j] = fg * co[j] + ig * ct;
        s += cn[j];
    }
    float mu  = block_sum(s, sred) * (1.f/1024.f);
    float vs = 0.f;
    #pragma unroll
    for (int j = 0; j < 4; ++j) { float d = cn[j] - mu; vs += d*d; }
    float var = block_sum(vs, sred) * (1.f/1024.f);
    float rs  = rsqrtf(var + LN_EPS);

    float4 cw, hw; f16x4 h16w;
    #pragma unroll
    for (int j = 0; j < 4; ++j) {
        float cv = (cn[j] - mu) * rs;
        float hv = og[j] * tanhf(cv);
        ((float*)&cw)[j] = cv;
        ((float*)&hw)[j] = hv;
        h16w[j] = (half_t)hv;
    }
    *(float4*)&cst[cb] = cw;
    *(f16x4*)&hs[cb]   = h16w;
    if (final_step) *(float4*)&hf[cb] = hw;
}

// cells(t): blocks 0..511 -> cell1(t) row b; 512..1023 -> cell2(t-1) row b-512.
__global__ __launch_bounds__(256) void cells_kernel(
    const half_t* __restrict__ preA1_rd, const half_t* __restrict__ preB1,
    const half_t* __restrict__ preA2,    const half_t* __restrict__ preB2,
    const float* __restrict__ b1, const float* __restrict__ b2,
    float* __restrict__ c0, float* __restrict__ c1,
    half_t* __restrict__ h0s, half_t* __restrict__ h1s,
    float* __restrict__ h0f, float* __restrict__ h1f, int st)
{
    const int blk = blockIdx.x;
    if (blk < 512) {
        cell_block(blk, preA1_rd, preB1, b1, c0, h0s, h0f, st == 63);
    } else {
        if (st == 0) return;
        cell_block(blk - 512, preA2, preB2, b2, c1, h1s, h1f, false);
    }
}

// final cell2(63)
__global__ __launch_bounds__(256) void cells_final(
    const half_t* __restrict__ preA2, const half_t* __restrict__ preB2,
    const float* __restrict__ b2,
    float* __restrict__ c1, half_t* __restrict__ h1s, float* __restrict__ h1f)
{
    cell_block(blockIdx.x, preA2, preB2, b2, c1, h1s, h1f, true);
}

// ---------------------------------------------------------------------------
// gemms(t): 512 WGs, one full-machine round. wg = ylo + 8*(x + 4*(z + 4*yhi)):
//   z0: preA2(t)   = h0(t)   @ wx2^T
//   z1: preB2(t)   = h1(t-1) @ wh2^T
//   z2: preB1(t+1) = h0(t)   @ wh1^T
//   z3: preA1(t+1) = X(t+1)  @ wx1^T   (skipped at st==63)
// All operands from earlier launches -> plain global_load_lds everywhere.
// y%8 == dispatch%8 -> weight panels XCD-pinned across all 64 steps.
// ---------------------------------------------------------------------------
__global__ __launch_bounds__(256, 2) void step_gemm4(
    const half_t* __restrict__ X,
    const half_t* __restrict__ wx1c, const half_t* __restrict__ wx2c,
    const half_t* __restrict__ wh1t, const half_t* __restrict__ wh2t,
    half_t* __restrict__ preA1_wr, half_t* __restrict__ preA2,
    half_t* __restrict__ preB1, half_t* __restrict__ preB2,
    const half_t* __restrict__ h0s, const half_t* __restrict__ h1s, int st)
{
    __shared__ __align__(16) unsigned char sA[2][16384];
    __shared__ __align__(16) unsigned char sB[2][16384];

    const int wg = blockIdx.x;
    const int ylo = wg & 7;
    int r = wg >> 3;
    const int x = r & 3; r >>= 2;
    const int z = r & 3; r >>= 2;
    const int y = ylo + 8 * r;

    if (z == 3 && st == 63) return;      // no t+1

    const half_t* A; const half_t* B; half_t* C; size_t lda;
    if (z == 0)      { A = h0s; lda = 1024; B = wx2c; C = preA2; }
    else if (z == 1) { A = h1s; lda = 1024; B = wh2t; C = preB2; }
    else if (z == 2) { A = h0s; lda = 1024; B = wh1t; C = preB1; }
    else { A = X + (size_t)(st+1) * 1024; lda = 65536; B = wx1c; C = preA1_wr; }

    const int t = threadIdx.x, l = t & 63, w = t >> 6;
    const int wr = (w >> 1) * 64, wc = (w & 1) * 64;
    const int rowbase = x * 128, colbase = y * 128;

    int srow[4], sch[4];
    #pragma unroll
    for (int i = 0; i < 4; ++i) {
        int s = (w*4 + i)*64 + l;
        srow[i] = s >> 3;
        sch[i]  = ((s & 7) ^ (srow[i] & 7)) * 8;
    }

    f32x4 acc[4][4];
    #pragma unroll
    for (int m = 0; m < 4; ++m)
        #pragma unroll
        for (int n = 0; n < 4; ++n) acc[m][n] = (f32x4)(0.f);

    auto stage = [&](int kt, int buf) {
        const int ko = kt * 64;
        #pragma unroll
        for (int i = 0; i < 4; ++i) {
            gll16(A + (size_t)(rowbase+srow[i])*lda + ko + sch[i], &sA[buf][(w*4+i)*1024]);
            gll16(B + (size_t)(colbase+srow[i])*1024 + ko + sch[i], &sB[buf][(w*4+i)*1024]);
        }
    };

    stage(0, 0);
    for (int kt = 0; kt < 16; ++kt) {
        const int buf = kt & 1;
        __syncthreads();                 // vmcnt(0): buf ready; WAR-safe for buf^1
        if (kt + 1 < 16) stage(kt + 1, buf ^ 1);
        #pragma unroll
        for (int kk = 0; kk < 2; ++kk) {
            const int chunk = kk*4 + (l >> 4);
            f16x8 bfr[4];
            #pragma unroll
            for (int n = 0; n < 4; ++n) {
                int rowb = wc + n*16 + (l & 15);
                bfr[n] = *(const f16x8*)&sB[buf][rowb*128 + ((chunk ^ (rowb & 7)) << 4)];
            }
            #pragma unroll
            for (int m = 0; m < 4; ++m) {
                int rowa = wr + m*16 + (l & 15);
                f16x8 af = *(const f16x8*)&sA[buf][rowa*128 + ((chunk ^ (rowa & 7)) << 4)];
                #pragma unroll
                for (int n = 0; n < 4; ++n)
                    acc[m][n] = __builtin_amdgcn_mfma_f32_16x16x32_f16(af, bfr[n], acc[m][n], 0, 0, 0);
            }
        }
    }

    // epilogue: C/D layout col = lane&15, row = (lane>>4)*4 + reg  [m89/m91]
    #pragma unroll
    for (int m = 0; m < 4; ++m) {
        int row0 = rowbase + wr + m*16 + (l >> 4)*4;
        #pragma unroll
        for (int n = 0; n < 4; ++n) {
            int col = colbase + wc + n*16 + (l & 15);
            #pragma unroll
            for (int r2 = 0; r2 < 4; ++r2)
                C[(size_t)(row0+r2)*4096 + col] = (half_t)acc[m][n][r2];
        }
    }
}

struct GArgs {
    const half_t* A; const half_t* B; const float* bias; void* C;
    int lda, ldb, K, ldc, outhalf;
};

// ---------------------------------------------------------------------------
// Multi-set fp16 GEMM (fc1 / fc2 / fallback): up to 3 independent C=A*B^T.
// rowpin=0: y%8 pinned to XCD (weight/B-panel reuse across dispatches).
// rowpin=1: x%8 pinned to XCD (A is the large operand, e.g. fc1: each XCD
//           reads 1/8 of A instead of all of it -> kills the 4x over-fetch).
// ---------------------------------------------------------------------------
__global__ __launch_bounds__(256) void gemm_ms(GArgs g0, GArgs g1, GArgs g2,
                                               int gx, int gy, int gz, int rowpin)
{
    const int d = blockIdx.x;
    int x, y, z;
    if (rowpin) {
        const int xlo = d & 7;
        int r = d >> 3;
        y = r % gy;  r /= gy;
        z = r % gz;
        x = xlo + 8 * (r / gz);
    } else {
        const int ylo = d & 7;
        int r = d >> 3;
        x = r % gx;  r /= gx;
        z = r % gz;
        y = ylo + 8 * (r / gz);
    }

    const GArgs g = (z == 0) ? g0 : (z == 1 ? g1 : g2);

    __shared__ __align__(16) unsigned char sA[2][16384];
    __shared__ __align__(16) unsigned char sB[2][16384];

    const int t  = threadIdx.x;
    const int l  = t & 63;
    const int w  = t >> 6;
    const int wr = (w >> 1) * 64;
    const int wc = (w & 1)  * 64;
    const int rowbase = x * 128;
    const int colbase = y * 128;

    f32x4 acc[4][4];
    #pragma unroll
    for (int m = 0; m < 4; ++m)
        #pragma unroll
        for (int n = 0; n < 4; ++n) acc[m][n] = (f32x4)(0.f);

    int srow[4], sch[4];
    #pragma unroll
    for (int i = 0; i < 4; ++i) {
        int s = (w*4 + i)*64 + l;
        srow[i] = s >> 3;
        sch[i]  = ((s & 7) ^ (srow[i] & 7)) * 8;
    }

    const int nkt = g.K >> 6;

    auto stage = [&](int kt, int buf) {
        const int ko = kt * 64;
        #pragma unroll
        for (int i = 0; i < 4; ++i) {
            gll16(g.A + (size_t)(rowbase+srow[i])*g.lda + ko + sch[i], &sA[buf][(w*4+i)*1024]);
            gll16(g.B + (size_t)(colbase+srow[i])*g.ldb + ko + sch[i], &sB[buf][(w*4+i)*1024]);
        }
    };

    stage(0, 0);
    for (int kt = 0; kt < nkt; ++kt) {
        const int buf = kt & 1;
        __syncthreads();
        if (kt + 1 < nkt) stage(kt + 1, buf ^ 1);
        #pragma unroll
        for (int kk = 0; kk < 2; ++kk) {
            const int chunk = kk*4 + (l >> 4);
            f16x8 bfr[4];
            #pragma unroll
            for (int n = 0; n < 4; ++n) {
                int rowb = wc + n*16 + (l & 15);
                bfr[n] = *(const f16x8*)&sB[buf][rowb*128 + ((chunk ^ (rowb & 7)) << 4)];
            }
            #pragma unroll
            for (int m = 0; m < 4; ++m) {
                int rowa = wr + m*16 + (l & 15);
                f16x8 af = *(const f16x8*)&sA[buf][rowa*128 + ((chunk ^ (rowa & 7)) << 4)];
                #pragma unroll
                for (int n = 0; n < 4; ++n)
                    acc[m][n] = __builtin_amdgcn_mfma_f32_16x16x32_f16(af, bfr[n], acc[m][n], 0, 0, 0);
            }
        }
    }

    #pragma unroll
    for (int m = 0; m < 4; ++m) {
        int row0 = rowbase + wr + m*16 + (l >> 4)*4;
        #pragma unroll
        for (int n = 0; n < 4; ++n) {
            int col = colbase + wc + n*16 + (l & 15);
            float bv = g.bias ? g.bias[col] : 0.f;
            #pragma unroll
            for (int r2 = 0; r2 < 4; ++r2) {
                float v = acc[m][n][r2] + bv;
                if (g.outhalf) ((half_t*)g.C)[(size_t)(row0+r2)*g.ldc + col] = (half_t)v;
                else           ((float*)g.C)[(size_t)(row0+r2)*g.ldc + col] = v;
            }
        }
    }
}

// ---------------------------------------------------------------------------
__global__ __launch_bounds__(256) void transpose_wh_cvt(
    const float* __restrict__ wh1, const float* __restrict__ wh2,
    half_t* __restrict__ o1, half_t* __restrict__ o2)
{
    __shared__ float tile[64][65];
    const int z = blockIdx.z;
    const float* src = (z < 4 ? wh1 : wh2) + (size_t)(z & 3) * 1024 * 1024;
    half_t*      dst = (z < 4 ? o1  : o2 ) + (size_t)(z & 3) * 1024 * 1024;
    const int kb = blockIdx.x * 64, nb = blockIdx.y * 64;
    const int t = threadIdx.x;
    #pragma unroll
    for (int i = 0; i < 16; ++i) {
        int idx = t + i*256, r = idx >> 6, c = idx & 63;
        tile[r][c] = src[(size_t)(kb + r)*1024 + nb + c];
    }
    __syncthreads();
    #pragma unroll
    for (int i = 0; i < 16; ++i) {
        int idx = t + i*256, r = idx >> 6, c = idx & 63;
        dst[(size_t)(nb + r)*1024 + kb + c] = (half_t)tile[c][r];
    }
}

__global__ __launch_bounds__(256) void cvt_f32_f16(
    const float* __restrict__ in, half_t* __restrict__ out, int n8)
{
    int i = blockIdx.x * 256 + threadIdx.x;
    if (i >= n8) return;
    float4 lo = ((const float4*)in)[2*i];
    float4 hi = ((const float4*)in)[2*i + 1];
    union { uint4 v; half_t h[8]; } r;
    r.h[0]=(half_t)lo.x; r.h[1]=(half_t)lo.y; r.h[2]=(half_t)lo.z; r.h[3]=(half_t)lo.w;
    r.h[4]=(half_t)hi.x; r.h[5]=(half_t)hi.y; r.h[6]=(half_t)hi.z; r.h[7]=(half_t)hi.w;
    ((uint4*)out)[i] = r.v;
}

__global__ __launch_bounds__(256) void pack_out(
    const float* __restrict__ h0, const float* __restrict__ h1,
    const float* __restrict__ c0, const float* __restrict__ c1, float* __restrict__ out)
{
    const int NSZ = 512 * 1024;
    int i = blockIdx.x * 256 + threadIdx.x;
    out[NSZ     + i] = h0[i];
    out[2*NSZ   + i] = h1[i];
    out[3*NSZ   + i] = c0[i];
    out[4*NSZ   + i] = c1[i];
}

extern "C" void kernel_launch(void* const* d_in, const int* in_sizes, int n_in,
                              void* d_out, int out_size, void* d_ws, size_t ws_size,
                              hipStream_t stream)
{
    const float* obs   = (const float*)d_in[0];
    const float* fc1_w = (const float*)d_in[1];
    const float* fc1_b = (const float*)d_in[2];
    const float* wx1   = (const float*)d_in[3];
    const float* wh1   = (const float*)d_in[4];
    const float* b1    = (const float*)d_in[5];
    const float* wx2   = (const float*)d_in[6];
    const float* wh2   = (const float*)d_in[7];
    const float* b2    = (const float*)d_in[8];
    const float* fc2_w = (const float*)d_in[9];
    const float* fc2_b = (const float*)d_in[10];
    float* out = (float*)d_out;

    char* ws = (char*)d_ws;
    size_t off = 0;
    auto carve = [&](size_t bytes) -> char* {
        char* p = ws + off; off += (bytes + 255) & ~(size_t)255; return p;
    };
    half_t* obs16 = (half_t*)carve((size_t)512*64*512*2);   // 33.6 MB
    half_t* wx1c  = (half_t*)carve((size_t)4096*1024*2);
    half_t* wh1t  = (half_t*)carve((size_t)4096*1024*2);
    half_t* wx2c  = (half_t*)carve((size_t)4096*1024*2);
    half_t* wh2t  = (half_t*)carve((size_t)4096*1024*2);
    half_t* fc1c  = (half_t*)carve((size_t)1024*512*2);
    half_t* fc2c  = (half_t*)carve((size_t)1024*1024*2);
    half_t* preA1a= (half_t*)carve((size_t)512*4096*2);     // parity 0
    half_t* preA1b= (half_t*)carve((size_t)512*4096*2);     // parity 1
    half_t* preA2 = (half_t*)carve((size_t)512*4096*2);
    half_t* preB1 = (half_t*)carve((size_t)512*4096*2);
    half_t* preB2 = (half_t*)carve((size_t)512*4096*2);
    half_t* h0s   = (half_t*)carve((size_t)512*1024*2);
    half_t* h1s   = (half_t*)carve((size_t)512*1024*2);
    float*  h0f   = (float*) carve((size_t)512*1024*4);
    float*  h1f   = (float*) carve((size_t)512*1024*4);
    float*  c0    = (float*) carve((size_t)512*1024*4);
    float*  c1    = (float*) carve((size_t)512*1024*4);

    const size_t X_bytes = (size_t)512*64*1024*2;           // 67 MB
    bool modeB = (off + X_bytes) <= ws_size;
    half_t* X = (half_t*)carve(modeB ? X_bytes : (size_t)512*1024*2);

    hipMemsetAsync(h1s, 0, (size_t)512*1024*2, stream);
    hipMemsetAsync(c0,  0, (size_t)512*1024*4, stream);
    hipMemsetAsync(c1,  0, (size_t)512*1024*4, stream);
    hipMemsetAsync(preB1, 0, (size_t)512*4096*2, stream);   // h0(-1)=0

    // one-time conversions
    cvt_f32_f16<<<8192, 256, 0, stream>>>(obs,   obs16, 512*64*512/8);
    cvt_f32_f16<<<2048, 256, 0, stream>>>(wx1,   wx1c,  4*1024*1024/8);
    cvt_f32_f16<<<2048, 256, 0, stream>>>(wx2,   wx2c,  4*1024*1024/8);
    cvt_f32_f16<<<256,  256, 0, stream>>>(fc1_w, fc1c,  1024*512/8);
    cvt_f32_f16<<<512,  256, 0, stream>>>(fc2_w, fc2c,  1024*1024/8);
    transpose_wh_cvt<<<dim3(16,16,8), 256, 0, stream>>>(wh1, wh2, wh1t, wh2t);

    GArgs Z{};
    auto ga = [](const half_t* A, int lda, const half_t* B, int ldb, int K,
                 const float* bias, void* C, int ldc, int outhalf) {
        GArgs g; g.A=A; g.B=B; g.bias=bias; g.C=C;
        g.lda=lda; g.ldb=ldb; g.K=K; g.ldc=ldc; g.outhalf=outhalf; return g;
    };

    if (modeB) {
        // X = obs @ fc1^T + b : M=32768, N=1024, K=512.  ROW-pinned XCD decode:
        // A (obs16) is the big operand -> each XCD reads its own 1/8 of A.
        gemm_ms<<<256*8, 256, 0, stream>>>(
            ga(obs16, 512, fc1c, 512, 512, fc1_b, X, 1024, 1), Z, Z, 256, 8, 1, 1);
        // preA1 parity0 = X(0) @ wx1^T
        gemm_ms<<<4*32, 256, 0, stream>>>(
            ga(X, 65536, wx1c, 1024, 1024, nullptr, preA1a, 4096, 1), Z, Z, 4, 32, 1, 0);

        for (int st = 0; st < 64; ++st) {
            const half_t* preA1_rd = (st & 1) ? preA1b : preA1a;
            half_t*       preA1_wr = (st & 1) ? preA1a : preA1b;
            cells_kernel<<<1024, 256, 0, stream>>>(
                preA1_rd, preB1, preA2, preB2, b1, b2,
                c0, c1, h0s, h1s, h0f, h1f, st);
            step_gemm4<<<512, 256, 0, stream>>>(
                X, wx1c, wx2c, wh1t, wh2t,
                preA1_wr, preA2, preB1, preB2, h0s, h1s, st);
        }
        cells_final<<<512, 256, 0, stream>>>(preA2, preB2, b2, c1, h1s, h1f);
    } else {
        // fallback: per-step small GEMMs (correct, slower)
        for (int st = 0; st < 64; ++st) {
            gemm_ms<<<4*8, 256, 0, stream>>>(
                ga(obs16 + (size_t)st*512, 64*512, fc1c, 512, 512, fc1_b, X, 1024, 1),
                Z, Z, 4, 8, 1, 0);
            gemm_ms<<<4*32*2, 256, 0, stream>>>(
                ga(X, 1024,   wx1c, 1024, 1024, nullptr, preA1a, 4096, 1),
                ga(h0s, 1024, wh1t, 1024, 1024, nullptr, preB1, 4096, 1), Z, 4, 32, 2, 0);
            cells_kernel<<<1024, 256, 0, stream>>>(
                preA1a, preB1, preA2, preB2, b1, b2,
                c0, c1, h0s, h1s, h0f, h1f, st);
            gemm_ms<<<4*32*2, 256, 0, stream>>>(
                ga(h0s, 1024, wx2c, 1024, 1024, nullptr, preA2, 4096, 1),
                ga(h1s, 1024, wh2t, 1024, 1024, nullptr, preB2, 4096, 1), Z, 4, 32, 2, 0);
        }
        cells_final<<<512, 256, 0, stream>>>(preA2, preB2, b2, c1, h1s, h1f);
    }

    // fc2: logit = h1 @ fc2_w^T + fc2_b -> d_out[0 : 512*1024) fp32
    gemm_ms<<<4*8, 256, 0, stream>>>(
        ga(h1s, 1024, fc2c, 1024, 1024, fc2_b, out, 1024, 0), Z, Z, 4, 8, 1, 0);
    pack_out<<<2048, 256, 0, stream>>>(h0f, h1f, c0, c1, out);
}

// Round 14
// 2255.279 us; speedup vs baseline: 1.5196x; 1.0591x over previous
//
#include <hip/hip_runtime.h>
#include <hip/hip_bf16.h>
#include <hip/hip_fp16.h>

using half_t = _Float16;
typedef __attribute__((ext_vector_type(8))) _Float16 f16x8;  // 8 fp16 = 4 VGPRs (MFMA frag)
typedef __attribute__((ext_vector_type(4))) _Float16 f16x4;
typedef __attribute__((ext_vector_type(4))) float f32x4;

#define LN_EPS 1e-5f

// async global->LDS, 16B per lane. gptr is PER-LANE, ldsbase is wave-uniform;
// HW writes ldsbase + lane*16.  [m97/m173 pattern]
__device__ inline void gll16(const void* g, void* ldsbase) {
    __builtin_amdgcn_global_load_lds(
        (const __attribute__((address_space(1))) void*)g,
        (__attribute__((address_space(3))) void*)ldsbase, 16, 0, 0);
}

// ---------------------------------------------------------------------------
// Block-per-row LN-LSTM cell: 256 thr, 4 contiguous elems/thread, LDS reduce.
// ---------------------------------------------------------------------------
__device__ inline float block_sum(float v, float* sred) {
    #pragma unroll
    for (int off = 32; off; off >>= 1) v += __shfl_down(v, off, 64);
    __syncthreads();
    if ((threadIdx.x & 63) == 0) sred[threadIdx.x >> 6] = v;
    __syncthreads();
    return sred[0] + sred[1] + sred[2] + sred[3];
}

__device__ inline void cell_block(
    int b, const half_t* __restrict__ preA, const half_t* __restrict__ preB,
    const float* __restrict__ bias,
    float* __restrict__ cst, half_t* __restrict__ hs,
    float* __restrict__ hf, bool final_step)
{
    __shared__ float sred[4];
    const int t = threadIdx.x;
    const int hi = t * 4;
    const size_t pb = (size_t)b * 4096 + hi;
    const size_t cb = (size_t)b * 1024 + hi;

    float pre[4][4];
    #pragma unroll
    for (int g = 0; g < 4; ++g) {
        f16x4 a4 = *(const f16x4*)&preA[pb + g*1024];
        f16x4 v4 = *(const f16x4*)&preB[pb + g*1024];
        float4 bs = *(const float4*)&bias[g*1024 + hi];
        pre[g][0] = (float)a4[0] + (float)v4[0] + bs.x;
        pre[g][1] = (float)a4[1] + (float)v4[1] + bs.y;
        pre[g][2] = (float)a4[2] + (float)v4[2] + bs.z;
        pre[g][3] = (float)a4[3] + (float)v4[3] + bs.w;
    }
    float4 c4 = *(const float4*)&cst[cb];
    float co[4] = {c4.x, c4.y, c4.z, c4.w};

    float cn[4], og[4], s = 0.f;
    #pragma unroll
    for (int j = 0; j < 4; ++j) {
        float ig = 1.f / (1.f + expf(-pre[0][j]));
        float fg = 1.f / (1.f + expf(-pre[1][j]));
        og[j]    = 1.f / (1.f + expf(-pre[2][j]));
        float ct = tanhf(pre[3][j]);
        cn[j] = fg * co[j] + ig * ct;
        s += cn[j];
    }
    float mu  = block_sum(s, sred) * (1.f/1024.f);
    float vs = 0.f;
    #pragma unroll
    for (int j = 0; j < 4; ++j) { float d = cn[j] - mu; vs += d*d; }
    float var = block_sum(vs, sred) * (1.f/1024.f);
    float rs  = rsqrtf(var + LN_EPS);

    float4 cw, hw; f16x4 h16w;
    #pragma unroll
    for (int j = 0; j < 4; ++j) {
        float cv = (cn[j] - mu) * rs;
        float hv = og[j] * tanhf(cv);
        ((float*)&cw)[j] = cv;
        ((float*)&hw)[j] = hv;
        h16w[j] = (half_t)hv;
    }
    *(float4*)&cst[cb] = cw;
    *(f16x4*)&hs[cb]   = h16w;
    if (final_step) *(float4*)&hf[cb] = hw;
}

// cells(t): blocks 0..511 -> cell1(t) row b; 512..1023 -> cell2(t-1) row b-512.
__global__ __launch_bounds__(256) void cells_kernel(
    const half_t* __restrict__ preA1, const half_t* __restrict__ preB1,
    const half_t* __restrict__ preA2, const half_t* __restrict__ preB2,
    const float* __restrict__ b1x, const float* __restrict__ b2,
    float* __restrict__ c0, float* __restrict__ c1,
    half_t* __restrict__ h0s, half_t* __restrict__ h1s,
    float* __restrict__ h0f, float* __restrict__ h1f, int st)
{
    const int blk = blockIdx.x;
    if (blk < 512) {
        cell_block(blk, preA1, preB1, b1x, c0, h0s, h0f, st == 63);
    } else {
        if (st == 0) return;
        cell_block(blk - 512, preA2, preB2, b2, c1, h1s, h1f, false);
    }
}

// final cell2(63)
__global__ __launch_bounds__(256) void cells_final(
    const half_t* __restrict__ preA2, const half_t* __restrict__ preB2,
    const float* __restrict__ b2,
    float* __restrict__ c1, half_t* __restrict__ h1s, float* __restrict__ h1f)
{
    cell_block(blockIdx.x, preA2, preB2, b2, c1, h1s, h1f, true);
}

// ---------------------------------------------------------------------------
// gemms(t): 512 WGs. wg = ylo + 8*(x + 4*(z + 4*yhi)):
//   z0: preA2(t)   = h0(t)   @ wx2^T            (K=1024)
//   z1: preB2(t)   = h1(t-1) @ wh2^T            (K=1024)
//   z2: preB1(t+1) = h0(t)   @ wh1^T            (K=1024)
//   z3: preA1(t+1) = obs16(t+1) @ W1x^T         (K=512, fc1 folded into W1x;
//       skipped at st==63; finishes early -> dynamic backfill)
// y%8 == dispatch%8 -> weight panels XCD-pinned across all 64 steps.
// ---------------------------------------------------------------------------
__global__ __launch_bounds__(256, 2) void step_gemm4(
    const half_t* __restrict__ obs16,
    const half_t* __restrict__ W1x, const half_t* __restrict__ wx2c,
    const half_t* __restrict__ wh1t, const half_t* __restrict__ wh2t,
    half_t* __restrict__ preA1, half_t* __restrict__ preA2,
    half_t* __restrict__ preB1, half_t* __restrict__ preB2,
    const half_t* __restrict__ h0s, const half_t* __restrict__ h1s, int st)
{
    __shared__ __align__(16) unsigned char sA[2][16384];
    __shared__ __align__(16) unsigned char sB[2][16384];

    const int wg = blockIdx.x;
    const int ylo = wg & 7;
    int r = wg >> 3;
    const int x = r & 3; r >>= 2;
    const int z = r & 3; r >>= 2;
    const int y = ylo + 8 * r;

    if (z == 3 && st == 63) return;      // no t+1

    const half_t* A; const half_t* B; half_t* C; size_t lda, ldb; int nkt;
    if (z == 0)      { A = h0s; lda = 1024; B = wx2c; ldb = 1024; C = preA2; nkt = 16; }
    else if (z == 1) { A = h1s; lda = 1024; B = wh2t; ldb = 1024; C = preB2; nkt = 16; }
    else if (z == 2) { A = h0s; lda = 1024; B = wh1t; ldb = 1024; C = preB1; nkt = 16; }
    else { A = obs16 + (size_t)(st+1) * 512; lda = 32768; B = W1x; ldb = 512; C = preA1; nkt = 8; }

    const int t = threadIdx.x, l = t & 63, w = t >> 6;
    const int wr = (w >> 1) * 64, wc = (w & 1) * 64;
    const int rowbase = x * 128, colbase = y * 128;

    int srow[4], sch[4];
    #pragma unroll
    for (int i = 0; i < 4; ++i) {
        int s = (w*4 + i)*64 + l;
        srow[i] = s >> 3;
        sch[i]  = ((s & 7) ^ (srow[i] & 7)) * 8;
    }

    f32x4 acc[4][4];
    #pragma unroll
    for (int m = 0; m < 4; ++m)
        #pragma unroll
        for (int n = 0; n < 4; ++n) acc[m][n] = (f32x4)(0.f);

    auto stage = [&](int kt, int buf) {
        const int ko = kt * 64;
        #pragma unroll
        for (int i = 0; i < 4; ++i) {
            gll16(A + (size_t)(rowbase+srow[i])*lda + ko + sch[i], &sA[buf][(w*4+i)*1024]);
            gll16(B + (size_t)(colbase+srow[i])*ldb + ko + sch[i], &sB[buf][(w*4+i)*1024]);
        }
    };

    stage(0, 0);
    for (int kt = 0; kt < nkt; ++kt) {
        const int buf = kt & 1;
        __syncthreads();                 // vmcnt(0): buf ready; WAR-safe for buf^1
        if (kt + 1 < nkt) stage(kt + 1, buf ^ 1);
        #pragma unroll
        for (int kk = 0; kk < 2; ++kk) {
            const int chunk = kk*4 + (l >> 4);
            f16x8 bfr[4];
            #pragma unroll
            for (int n = 0; n < 4; ++n) {
                int rowb = wc + n*16 + (l & 15);
                bfr[n] = *(const f16x8*)&sB[buf][rowb*128 + ((chunk ^ (rowb & 7)) << 4)];
            }
            #pragma unroll
            for (int m = 0; m < 4; ++m) {
                int rowa = wr + m*16 + (l & 15);
                f16x8 af = *(const f16x8*)&sA[buf][rowa*128 + ((chunk ^ (rowa & 7)) << 4)];
                #pragma unroll
                for (int n = 0; n < 4; ++n)
                    acc[m][n] = __builtin_amdgcn_mfma_f32_16x16x32_f16(af, bfr[n], acc[m][n], 0, 0, 0);
            }
        }
    }

    // epilogue: C/D layout col = lane&15, row = (lane>>4)*4 + reg  [m89/m91]
    #pragma unroll
    for (int m = 0; m < 4; ++m) {
        int row0 = rowbase + wr + m*16 + (l >> 4)*4;
        #pragma unroll
        for (int n = 0; n < 4; ++n) {
            int col = colbase + wc + n*16 + (l & 15);
            #pragma unroll
            for (int r2 = 0; r2 < 4; ++r2)
                C[(size_t)(row0+r2)*4096 + col] = (half_t)acc[m][n][r2];
        }
    }
}

struct GArgs {
    const half_t* A; const half_t* B; const float* bias; void* C;
    int lda, ldb, K, ldc, outhalf;
};

// ---------------------------------------------------------------------------
// Multi-set fp16 GEMM (prologue / fc2): up to 3 independent C=A*B^T.
// rowpin=1 pins x%8 to XCD (use when A is the large operand).
// ---------------------------------------------------------------------------
__global__ __launch_bounds__(256) void gemm_ms(GArgs g0, GArgs g1, GArgs g2,
                                               int gx, int gy, int gz, int rowpin)
{
    const int d = blockIdx.x;
    int x, y, z;
    if (rowpin) {
        const int xlo = d & 7;
        int r = d >> 3;
        y = r % gy;  r /= gy;
        z = r % gz;
        x = xlo + 8 * (r / gz);
    } else {
        const int ylo = d & 7;
        int r = d >> 3;
        x = r % gx;  r /= gx;
        z = r % gz;
        y = ylo + 8 * (r / gz);
    }

    const GArgs g = (z == 0) ? g0 : (z == 1 ? g1 : g2);

    __shared__ __align__(16) unsigned char sA[2][16384];
    __shared__ __align__(16) unsigned char sB[2][16384];

    const int t  = threadIdx.x;
    const int l  = t & 63;
    const int w  = t >> 6;
    const int wr = (w >> 1) * 64;
    const int wc = (w & 1)  * 64;
    const int rowbase = x * 128;
    const int colbase = y * 128;

    f32x4 acc[4][4];
    #pragma unroll
    for (int m = 0; m < 4; ++m)
        #pragma unroll
        for (int n = 0; n < 4; ++n) acc[m][n] = (f32x4)(0.f);

    int srow[4], sch[4];
    #pragma unroll
    for (int i = 0; i < 4; ++i) {
        int s = (w*4 + i)*64 + l;
        srow[i] = s >> 3;
        sch[i]  = ((s & 7) ^ (srow[i] & 7)) * 8;
    }

    const int nkt = g.K >> 6;

    auto stage = [&](int kt, int buf) {
        const int ko = kt * 64;
        #pragma unroll
        for (int i = 0; i < 4; ++i) {
            gll16(g.A + (size_t)(rowbase+srow[i])*g.lda + ko + sch[i], &sA[buf][(w*4+i)*1024]);
            gll16(g.B + (size_t)(colbase+srow[i])*g.ldb + ko + sch[i], &sB[buf][(w*4+i)*1024]);
        }
    };

    stage(0, 0);
    for (int kt = 0; kt < nkt; ++kt) {
        const int buf = kt & 1;
        __syncthreads();
        if (kt + 1 < nkt) stage(kt + 1, buf ^ 1);
        #pragma unroll
        for (int kk = 0; kk < 2; ++kk) {
            const int chunk = kk*4 + (l >> 4);
            f16x8 bfr[4];
            #pragma unroll
            for (int n = 0; n < 4; ++n) {
                int rowb = wc + n*16 + (l & 15);
                bfr[n] = *(const f16x8*)&sB[buf][rowb*128 + ((chunk ^ (rowb & 7)) << 4)];
            }
            #pragma unroll
            for (int m = 0; m < 4; ++m) {
                int rowa = wr + m*16 + (l & 15);
                f16x8 af = *(const f16x8*)&sA[buf][rowa*128 + ((chunk ^ (rowa & 7)) << 4)];
                #pragma unroll
                for (int n = 0; n < 4; ++n)
                    acc[m][n] = __builtin_amdgcn_mfma_f32_16x16x32_f16(af, bfr[n], acc[m][n], 0, 0, 0);
            }
        }
    }

    #pragma unroll
    for (int m = 0; m < 4; ++m) {
        int row0 = rowbase + wr + m*16 + (l >> 4)*4;
        #pragma unroll
        for (int n = 0; n < 4; ++n) {
            int col = colbase + wc + n*16 + (l & 15);
            float bv = g.bias ? g.bias[col] : 0.f;
            #pragma unroll
            for (int r2 = 0; r2 < 4; ++r2) {
                float v = acc[m][n][r2] + bv;
                if (g.outhalf) ((half_t*)g.C)[(size_t)(row0+r2)*g.ldc + col] = (half_t)v;
                else           ((float*)g.C)[(size_t)(row0+r2)*g.ldc + col] = v;
            }
        }
    }
}

// ---------------------------------------------------------------------------
__global__ __launch_bounds__(256) void transpose_wh_cvt(
    const float* __restrict__ wh1, const float* __restrict__ wh2,
    half_t* __restrict__ o1, half_t* __restrict__ o2)
{
    __shared__ float tile[64][65];
    const int z = blockIdx.z;
    const float* src = (z < 4 ? wh1 : wh2) + (size_t)(z & 3) * 1024 * 1024;
    half_t*      dst = (z < 4 ? o1  : o2 ) + (size_t)(z & 3) * 1024 * 1024;
    const int kb = blockIdx.x * 64, nb = blockIdx.y * 64;
    const int t = threadIdx.x;
    #pragma unroll
    for (int i = 0; i < 16; ++i) {
        int idx = t + i*256, r = idx >> 6, c = idx & 63;
        tile[r][c] = src[(size_t)(kb + r)*1024 + nb + c];
    }
    __syncthreads();
    #pragma unroll
    for (int i = 0; i < 16; ++i) {
        int idx = t + i*256, r = idx >> 6, c = idx & 63;
        dst[(size_t)(nb + r)*1024 + kb + c] = (half_t)tile[c][r];
    }
}

// fc1_w (fp32 [1024][512]) -> fc1t (fp16 [512][1024])  (transpose + convert)
__global__ __launch_bounds__(256) void transpose_fc1(
    const float* __restrict__ fc1_w, half_t* __restrict__ fc1t)
{
    __shared__ float tile[64][65];
    const int hb = blockIdx.x * 64, ob = blockIdx.y * 64;   // grid (16, 8)
    const int t = threadIdx.x;
    #pragma unroll
    for (int i = 0; i < 16; ++i) {
        int idx = t + i*256, r = idx >> 6, c = idx & 63;
        tile[r][c] = fc1_w[(size_t)(hb + r)*512 + ob + c];
    }
    __syncthreads();
    #pragma unroll
    for (int i = 0; i < 16; ++i) {
        int idx = t + i*256, r = idx >> 6, c = idx & 63;
        fc1t[(size_t)(ob + r)*1024 + hb + c] = (half_t)tile[c][r];
    }
}

// b1x[j] = b1[j] + dot(wx1[j,:], fc1_b)   (fp32, j < 4096; one block per j)
__global__ __launch_bounds__(256) void fold_b1(
    const float* __restrict__ wx1, const float* __restrict__ fc1_b,
    const float* __restrict__ b1, float* __restrict__ b1x)
{
    __shared__ float sred[4];
    const int j = blockIdx.x, t = threadIdx.x;
    float4 wv = *(const float4*)&wx1[(size_t)j*1024 + t*4];
    float4 bv = *(const float4*)&fc1_b[t*4];
    float s = wv.x*bv.x + wv.y*bv.y + wv.z*bv.z + wv.w*bv.w;
    float tot = block_sum(s, sred);
    if (t == 0) b1x[j] = b1[j] + tot;
}

__global__ __launch_bounds__(256) void cvt_f32_f16(
    const float* __restrict__ in, half_t* __restrict__ out, int n8)
{
    int i = blockIdx.x * 256 + threadIdx.x;
    if (i >= n8) return;
    float4 lo = ((const float4*)in)[2*i];
    float4 hi = ((const float4*)in)[2*i + 1];
    union { uint4 v; half_t h[8]; } r;
    r.h[0]=(half_t)lo.x; r.h[1]=(half_t)lo.y; r.h[2]=(half_t)lo.z; r.h[3]=(half_t)lo.w;
    r.h[4]=(half_t)hi.x; r.h[5]=(half_t)hi.y; r.h[6]=(half_t)hi.z; r.h[7]=(half_t)hi.w;
    ((uint4*)out)[i] = r.v;
}

__global__ __launch_bounds__(256) void pack_out(
    const float* __restrict__ h0, const float* __restrict__ h1,
    const float* __restrict__ c0, const float* __restrict__ c1, float* __restrict__ out)
{
    const int NSZ = 512 * 1024;
    int i = blockIdx.x * 256 + threadIdx.x;
    out[NSZ     + i] = h0[i];
    out[2*NSZ   + i] = h1[i];
    out[3*NSZ   + i] = c0[i];
    out[4*NSZ   + i] = c1[i];
}

extern "C" void kernel_launch(void* const* d_in, const int* in_sizes, int n_in,
                              void* d_out, int out_size, void* d_ws, size_t ws_size,
                              hipStream_t stream)
{
    const float* obs   = (const float*)d_in[0];
    const float* fc1_w = (const float*)d_in[1];
    const float* fc1_b = (const float*)d_in[2];
    const float* wx1   = (const float*)d_in[3];
    const float* wh1   = (const float*)d_in[4];
    const float* b1    = (const float*)d_in[5];
    const float* wx2   = (const float*)d_in[6];
    const float* wh2   = (const float*)d_in[7];
    const float* b2    = (const float*)d_in[8];
    const float* fc2_w = (const float*)d_in[9];
    const float* fc2_b = (const float*)d_in[10];
    float* out = (float*)d_out;

    char* ws = (char*)d_ws;
    size_t off = 0;
    auto carve = [&](size_t bytes) -> char* {
        char* p = ws + off; off += (bytes + 255) & ~(size_t)255; return p;
    };
    half_t* obs16 = (half_t*)carve((size_t)512*64*512*2);   // 33.6 MB
    half_t* wx1c  = (half_t*)carve((size_t)4096*1024*2);    //  8.4 MB
    half_t* wh1t  = (half_t*)carve((size_t)4096*1024*2);
    half_t* wx2c  = (half_t*)carve((size_t)4096*1024*2);
    half_t* wh2t  = (half_t*)carve((size_t)4096*1024*2);
    half_t* fc1t  = (half_t*)carve((size_t)512*1024*2);     //  1.0 MB
    half_t* W1x   = (half_t*)carve((size_t)4096*512*2);     //  4.2 MB
    half_t* fc2c  = (half_t*)carve((size_t)1024*1024*2);
    float*  b1x   = (float*) carve((size_t)4096*4);
    half_t* preA1 = (half_t*)carve((size_t)512*4096*2);     //  4.2 MB
    half_t* preA2 = (half_t*)carve((size_t)512*4096*2);
    half_t* preB1 = (half_t*)carve((size_t)512*4096*2);
    half_t* preB2 = (half_t*)carve((size_t)512*4096*2);
    half_t* h0s   = (half_t*)carve((size_t)512*1024*2);
    half_t* h1s   = (half_t*)carve((size_t)512*1024*2);
    float*  h0f   = (float*) carve((size_t)512*1024*4);
    float*  h1f   = (float*) carve((size_t)512*1024*4);
    float*  c0    = (float*) carve((size_t)512*1024*4);
    float*  c1    = (float*) carve((size_t)512*1024*4);

    hipMemsetAsync(h1s, 0, (size_t)512*1024*2, stream);     // h1(-1)=0 for z1@st0
    hipMemsetAsync(c0,  0, (size_t)512*1024*4, stream);
    hipMemsetAsync(c1,  0, (size_t)512*1024*4, stream);
    hipMemsetAsync(preB1, 0, (size_t)512*4096*2, stream);   // h0(-1)=0

    // one-time conversions + fc1 fold
    cvt_f32_f16<<<8192, 256, 0, stream>>>(obs,   obs16, 512*64*512/8);
    cvt_f32_f16<<<2048, 256, 0, stream>>>(wx1,   wx1c,  4*1024*1024/8);
    cvt_f32_f16<<<2048, 256, 0, stream>>>(wx2,   wx2c,  4*1024*1024/8);
    cvt_f32_f16<<<512,  256, 0, stream>>>(fc2_w, fc2c,  1024*1024/8);
    transpose_wh_cvt<<<dim3(16,16,8), 256, 0, stream>>>(wh1, wh2, wh1t, wh2t);
    transpose_fc1<<<dim3(16,8), 256, 0, stream>>>(fc1_w, fc1t);
    fold_b1<<<4096, 256, 0, stream>>>(wx1, fc1_b, b1, b1x);

    GArgs Z{};
    auto ga = [](const half_t* A, int lda, const half_t* B, int ldb, int K,
                 const float* bias, void* C, int ldc, int outhalf) {
        GArgs g; g.A=A; g.B=B; g.bias=bias; g.C=C;
        g.lda=lda; g.ldb=ldb; g.K=K; g.ldc=ldc; g.outhalf=outhalf; return g;
    };

    // W1x[4096][512] = wx1c @ fc1t^T  (M=4096, N=512, K=1024; A large -> rowpin)
    gemm_ms<<<128, 256, 0, stream>>>(
        ga(wx1c, 1024, fc1t, 1024, 1024, nullptr, W1x, 512, 1), Z, Z, 32, 4, 1, 1);
    // preA1(0) = obs16(0) @ W1x^T  (M=512, N=4096, K=512)
    gemm_ms<<<128, 256, 0, stream>>>(
        ga(obs16, 32768, W1x, 512, 512, nullptr, preA1, 4096, 1), Z, Z, 4, 32, 1, 0);

    for (int st = 0; st < 64; ++st) {
        cells_kernel<<<1024, 256, 0, stream>>>(
            preA1, preB1, preA2, preB2, b1x, b2,
            c0, c1, h0s, h1s, h0f, h1f, st);
        step_gemm4<<<512, 256, 0, stream>>>(
            obs16, W1x, wx2c, wh1t, wh2t,
            preA1, preA2, preB1, preB2, h0s, h1s, st);
    }
    cells_final<<<512, 256, 0, stream>>>(preA2, preB2, b2, c1, h1s, h1f);

    // fc2: logit = h1 @ fc2_w^T + fc2_b -> d_out[0 : 512*1024) fp32
    gemm_ms<<<4*8, 256, 0, stream>>>(
        ga(h1s, 1024, fc2c, 1024, 1024, fc2_b, out, 1024, 0), Z, Z, 4, 8, 1, 0);
    pack_out<<<2048, 256, 0, stream>>>(h0f, h1f, c0, c1, out);
}

// Round 15
// 2027.912 us; speedup vs baseline: 1.6900x; 1.1121x over previous
//
#include <hip/hip_runtime.h>
#include <hip/hip_bf16.h>
#include <hip/hip_fp16.h>

using half_t = _Float16;
typedef __attribute__((ext_vector_type(8))) _Float16 f16x8;  // 8 fp16 = 4 VGPRs (MFMA frag)
typedef __attribute__((ext_vector_type(4))) _Float16 f16x4;
typedef __attribute__((ext_vector_type(4))) float f32x4;

#define LN_EPS 1e-5f

// async global->LDS, 16B per lane. gptr is PER-LANE, ldsbase is wave-uniform;
// HW writes ldsbase + lane*16.  [m97/m173 pattern]
__device__ inline void gll16(const void* g, void* ldsbase) {
    __builtin_amdgcn_global_load_lds(
        (const __attribute__((address_space(1))) void*)g,
        (__attribute__((address_space(3))) void*)ldsbase, 16, 0, 0);
}

// ---------------------------------------------------------------------------
// Block-per-row LN-LSTM cell: 256 thr, 4 contiguous elems/thread, LDS reduce.
// At final step writes h (fp32) and c (fp32) straight into d_out slots.
// ---------------------------------------------------------------------------
__device__ inline float block_sum(float v, float* sred) {
    #pragma unroll
    for (int off = 32; off; off >>= 1) v += __shfl_down(v, off, 64);
    __syncthreads();
    if ((threadIdx.x & 63) == 0) sred[threadIdx.x >> 6] = v;
    __syncthreads();
    return sred[0] + sred[1] + sred[2] + sred[3];
}

__device__ inline void cell_block(
    int b, const half_t* __restrict__ preA, const half_t* __restrict__ preB,
    const float* __restrict__ bias,
    float* __restrict__ cst, half_t* __restrict__ hs,
    float* __restrict__ hf, float* __restrict__ cf, bool final_step)
{
    __shared__ float sred[4];
    const int t = threadIdx.x;
    const int hi = t * 4;
    const size_t pb = (size_t)b * 4096 + hi;
    const size_t cb = (size_t)b * 1024 + hi;

    float pre[4][4];
    #pragma unroll
    for (int g = 0; g < 4; ++g) {
        f16x4 a4 = *(const f16x4*)&preA[pb + g*1024];
        f16x4 v4 = *(const f16x4*)&preB[pb + g*1024];
        float4 bs = *(const float4*)&bias[g*1024 + hi];
        pre[g][0] = (float)a4[0] + (float)v4[0] + bs.x;
        pre[g][1] = (float)a4[1] + (float)v4[1] + bs.y;
        pre[g][2] = (float)a4[2] + (float)v4[2] + bs.z;
        pre[g][3] = (float)a4[3] + (float)v4[3] + bs.w;
    }
    float4 c4 = *(const float4*)&cst[cb];
    float co[4] = {c4.x, c4.y, c4.z, c4.w};

    float cn[4], og[4], s = 0.f;
    #pragma unroll
    for (int j = 0; j < 4; ++j) {
        float ig = 1.f / (1.f + expf(-pre[0][j]));
        float fg = 1.f / (1.f + expf(-pre[1][j]));
        og[j]    = 1.f / (1.f + expf(-pre[2][j]));
        float ct = tanhf(pre[3][j]);
        cn[j] = fg * co[j] + ig * ct;
        s += cn[j];
    }
    float mu  = block_sum(s, sred) * (1.f/1024.f);
    float vs = 0.f;
    #pragma unroll
    for (int j = 0; j < 4; ++j) { float d = cn[j] - mu; vs += d*d; }
    float var = block_sum(vs, sred) * (1.f/1024.f);
    float rs  = rsqrtf(var + LN_EPS);

    float4 cw, hw; f16x4 h16w;
    #pragma unroll
    for (int j = 0; j < 4; ++j) {
        float cv = (cn[j] - mu) * rs;
        float hv = og[j] * tanhf(cv);
        ((float*)&cw)[j] = cv;
        ((float*)&hw)[j] = hv;
        h16w[j] = (half_t)hv;
    }
    *(float4*)&cst[cb] = cw;
    *(f16x4*)&hs[cb]   = h16w;
    if (final_step) {
        *(float4*)&hf[cb] = hw;
        *(float4*)&cf[cb] = cw;
    }
}

// cells(t): blocks 0..511 -> cell1(t) row b; 512..1023 -> cell2(t-1) row b-512.
__global__ __launch_bounds__(256) void cells_kernel(
    const half_t* __restrict__ preA1, const half_t* __restrict__ preB1,
    const half_t* __restrict__ preA2, const half_t* __restrict__ preB2,
    const float* __restrict__ b1x, const float* __restrict__ b2,
    float* __restrict__ c0, float* __restrict__ c1,
    half_t* __restrict__ h0s, half_t* __restrict__ h1s,
    float* __restrict__ out, int st)
{
    const int NSZ = 512 * 1024;
    const int blk = blockIdx.x;
    if (blk < 512) {
        cell_block(blk, preA1, preB1, b1x, c0, h0s,
                   out + NSZ, out + 3*NSZ, st == 63);
    } else {
        if (st == 0) return;
        cell_block(blk - 512, preA2, preB2, b2, c1, h1s,
                   nullptr, nullptr, false);
    }
}

// final cell2(63): h1 -> out[2*NSZ), c1 -> out[4*NSZ)
__global__ __launch_bounds__(256) void cells_final(
    const half_t* __restrict__ preA2, const half_t* __restrict__ preB2,
    const float* __restrict__ b2,
    float* __restrict__ c1, half_t* __restrict__ h1s, float* __restrict__ out)
{
    const int NSZ = 512 * 1024;
    cell_block(blockIdx.x, preA2, preB2, b2, c1, h1s,
               out + 2*NSZ, out + 4*NSZ, true);
}

// ---------------------------------------------------------------------------
// gemms(t): 512 WGs. wg = ylo + 8*(x + 4*(z + 4*yhi)):
//   z0: preA2(t)   = h0(t)   @ wx2^T            (K=1024)
//   z1: preB2(t)   = h1(t-1) @ wh2^T            (K=1024)
//   z2: preB1(t+1) = h0(t)   @ wh1^T            (K=1024)
//   z3: preA1(t+1) = obs(t+1) @ W1x^T           (K=512; fc1 folded into W1x;
//       A read as fp32 DIRECTLY from obs, reg-staged + cvt + late ds_write;
//       skipped at st==63; st==-1 prologue runs z3 only)
// y%8 == dispatch%8 -> weight panels XCD-pinned across all 64 steps.
// ---------------------------------------------------------------------------
__global__ __launch_bounds__(256, 2) void step_gemm4(
    const float* __restrict__ obsF,
    const half_t* __restrict__ W1x, const half_t* __restrict__ wx2c,
    const half_t* __restrict__ wh1t, const half_t* __restrict__ wh2t,
    half_t* __restrict__ preA1, half_t* __restrict__ preA2,
    half_t* __restrict__ preB1, half_t* __restrict__ preB2,
    const half_t* __restrict__ h0s, const half_t* __restrict__ h1s, int st)
{
    __shared__ __align__(16) unsigned char sA[2][16384];
    __shared__ __align__(16) unsigned char sB[2][16384];

    const int wg = blockIdx.x;
    const int ylo = wg & 7;
    int r = wg >> 3;
    const int x = r & 3; r >>= 2;
    const int z = r & 3; r >>= 2;
    const int y = ylo + 8 * r;

    const bool zx = (z == 3);
    if (zx && st == 63) return;          // no t+1
    if (st < 0 && !zx) return;           // prologue: z3 only

    const half_t* A; const half_t* B; half_t* C; size_t lda, ldb; int nkt;
    const float* Af = nullptr;
    if (z == 0)      { A = h0s; lda = 1024; B = wx2c; ldb = 1024; C = preA2; nkt = 16; }
    else if (z == 1) { A = h1s; lda = 1024; B = wh2t; ldb = 1024; C = preB2; nkt = 16; }
    else if (z == 2) { A = h0s; lda = 1024; B = wh1t; ldb = 1024; C = preB1; nkt = 16; }
    else { Af = obsF + (size_t)(st+1) * 512; A = nullptr; lda = 32768;
           B = W1x; ldb = 512; C = preA1; nkt = 8; }

    const int t = threadIdx.x, l = t & 63, w = t >> 6;
    const int wr = (w >> 1) * 64, wc = (w & 1) * 64;
    const int rowbase = x * 128, colbase = y * 128;

    int srow[4], sch[4];
    #pragma unroll
    for (int i = 0; i < 4; ++i) {
        int s = (w*4 + i)*64 + l;
        srow[i] = s >> 3;
        sch[i]  = ((s & 7) ^ (srow[i] & 7)) * 8;
    }

    f32x4 acc[4][4];
    #pragma unroll
    for (int m = 0; m < 4; ++m)
        #pragma unroll
        for (int n = 0; n < 4; ++n) acc[m][n] = (f32x4)(0.f);

    float4 fv[8];                        // z3: raw fp32 A in regs (late cvt+write)
    auto stageB = [&](int kt, int buf) {
        const int ko = kt * 64;
        #pragma unroll
        for (int i = 0; i < 4; ++i)
            gll16(B + (size_t)(colbase+srow[i])*ldb + ko + sch[i], &sB[buf][(w*4+i)*1024]);
    };
    auto stageA_h = [&](int kt, int buf) {
        const int ko = kt * 64;
        #pragma unroll
        for (int i = 0; i < 4; ++i)
            gll16(A + (size_t)(rowbase+srow[i])*lda + ko + sch[i], &sA[buf][(w*4+i)*1024]);
    };
    auto loadA_f = [&](int kt) {         // issue fp32 loads (plain -> compiler waits)
        const int ko = kt * 64;
        #pragma unroll
        for (int i = 0; i < 4; ++i) {
            const float* p = Af + (size_t)(rowbase+srow[i])*lda + ko + sch[i];
            fv[2*i]   = *(const float4*)p;
            fv[2*i+1] = *(const float4*)(p + 4);
        }
    };
    auto writeA_f = [&](int buf) {       // cvt + ds_write (after compute)
        #pragma unroll
        for (int i = 0; i < 4; ++i) {
            union { uint4 v; half_t h[8]; } rr;
            rr.h[0]=(half_t)fv[2*i].x;   rr.h[1]=(half_t)fv[2*i].y;
            rr.h[2]=(half_t)fv[2*i].z;   rr.h[3]=(half_t)fv[2*i].w;
            rr.h[4]=(half_t)fv[2*i+1].x; rr.h[5]=(half_t)fv[2*i+1].y;
            rr.h[6]=(half_t)fv[2*i+1].z; rr.h[7]=(half_t)fv[2*i+1].w;
            *(uint4*)&sA[buf][((w*4+i)*64 + l)*16] = rr.v;
        }
    };

    // prologue: stage K-tile 0
    stageB(0, 0);
    if (zx) { loadA_f(0); writeA_f(0); }
    else    stageA_h(0, 0);

    for (int kt = 0; kt < nkt; ++kt) {
        const int buf = kt & 1;
        __syncthreads();                 // vmcnt(0)+lgkm: buf ready; WAR-safe for buf^1
        const bool more = (kt + 1 < nkt);
        if (more) {
            stageB(kt + 1, buf ^ 1);
            if (zx) loadA_f(kt + 1);
            else    stageA_h(kt + 1, buf ^ 1);
        }
        #pragma unroll
        for (int kk = 0; kk < 2; ++kk) {
            const int chunk = kk*4 + (l >> 4);
            f16x8 bfr[4];
            #pragma unroll
            for (int n = 0; n < 4; ++n) {
                int rowb = wc + n*16 + (l & 15);
                bfr[n] = *(const f16x8*)&sB[buf][rowb*128 + ((chunk ^ (rowb & 7)) << 4)];
            }
            #pragma unroll
            for (int m = 0; m < 4; ++m) {
                int rowa = wr + m*16 + (l & 15);
                f16x8 af = *(const f16x8*)&sA[buf][rowa*128 + ((chunk ^ (rowa & 7)) << 4)];
                #pragma unroll
                for (int n = 0; n < 4; ++n)
                    acc[m][n] = __builtin_amdgcn_mfma_f32_16x16x32_f16(af, bfr[n], acc[m][n], 0, 0, 0);
            }
        }
        if (zx && more) writeA_f(buf ^ 1);   // loads aged a full compute phase
    }

    // epilogue: C/D layout col = lane&15, row = (lane>>4)*4 + reg  [m89/m91]
    #pragma unroll
    for (int m = 0; m < 4; ++m) {
        int row0 = rowbase + wr + m*16 + (l >> 4)*4;
        #pragma unroll
        for (int n = 0; n < 4; ++n) {
            int col = colbase + wc + n*16 + (l & 15);
            #pragma unroll
            for (int r2 = 0; r2 < 4; ++r2)
                C[(size_t)(row0+r2)*4096 + col] = (half_t)acc[m][n][r2];
        }
    }
}

struct GArgs {
    const half_t* A; const half_t* B; const float* bias; void* C;
    int lda, ldb, K, ldc, outhalf;
};

// ---------------------------------------------------------------------------
// Multi-set fp16 GEMM (prologue / fc2): up to 3 independent C=A*B^T.
// rowpin=1 pins x%8 to XCD (use when A is the large operand).
// ---------------------------------------------------------------------------
__global__ __launch_bounds__(256) void gemm_ms(GArgs g0, GArgs g1, GArgs g2,
                                               int gx, int gy, int gz, int rowpin)
{
    const int d = blockIdx.x;
    int x, y, z;
    if (rowpin) {
        const int xlo = d & 7;
        int r = d >> 3;
        y = r % gy;  r /= gy;
        z = r % gz;
        x = xlo + 8 * (r / gz);
    } else {
        const int ylo = d & 7;
        int r = d >> 3;
        x = r % gx;  r /= gx;
        z = r % gz;
        y = ylo + 8 * (r / gz);
    }

    const GArgs g = (z == 0) ? g0 : (z == 1 ? g1 : g2);

    __shared__ __align__(16) unsigned char sA[2][16384];
    __shared__ __align__(16) unsigned char sB[2][16384];

    const int t  = threadIdx.x;
    const int l  = t & 63;
    const int w  = t >> 6;
    const int wr = (w >> 1) * 64;
    const int wc = (w & 1)  * 64;
    const int rowbase = x * 128;
    const int colbase = y * 128;

    f32x4 acc[4][4];
    #pragma unroll
    for (int m = 0; m < 4; ++m)
        #pragma unroll
        for (int n = 0; n < 4; ++n) acc[m][n] = (f32x4)(0.f);

    int srow[4], sch[4];
    #pragma unroll
    for (int i = 0; i < 4; ++i) {
        int s = (w*4 + i)*64 + l;
        srow[i] = s >> 3;
        sch[i]  = ((s & 7) ^ (srow[i] & 7)) * 8;
    }

    const int nkt = g.K >> 6;

    auto stage = [&](int kt, int buf) {
        const int ko = kt * 64;
        #pragma unroll
        for (int i = 0; i < 4; ++i) {
            gll16(g.A + (size_t)(rowbase+srow[i])*g.lda + ko + sch[i], &sA[buf][(w*4+i)*1024]);
            gll16(g.B + (size_t)(colbase+srow[i])*g.ldb + ko + sch[i], &sB[buf][(w*4+i)*1024]);
        }
    };

    stage(0, 0);
    for (int kt = 0; kt < nkt; ++kt) {
        const int buf = kt & 1;
        __syncthreads();
        if (kt + 1 < nkt) stage(kt + 1, buf ^ 1);
        #pragma unroll
        for (int kk = 0; kk < 2; ++kk) {
            const int chunk = kk*4 + (l >> 4);
            f16x8 bfr[4];
            #pragma unroll
            for (int n = 0; n < 4; ++n) {
                int rowb = wc + n*16 + (l & 15);
                bfr[n] = *(const f16x8*)&sB[buf][rowb*128 + ((chunk ^ (rowb & 7)) << 4)];
            }
            #pragma unroll
            for (int m = 0; m < 4; ++m) {
                int rowa = wr + m*16 + (l & 15);
                f16x8 af = *(const f16x8*)&sA[buf][rowa*128 + ((chunk ^ (rowa & 7)) << 4)];
                #pragma unroll
                for (int n = 0; n < 4; ++n)
                    acc[m][n] = __builtin_amdgcn_mfma_f32_16x16x32_f16(af, bfr[n], acc[m][n], 0, 0, 0);
            }
        }
    }

    #pragma unroll
    for (int m = 0; m < 4; ++m) {
        int row0 = rowbase + wr + m*16 + (l >> 4)*4;
        #pragma unroll
        for (int n = 0; n < 4; ++n) {
            int col = colbase + wc + n*16 + (l & 15);
            float bv = g.bias ? g.bias[col] : 0.f;
            #pragma unroll
            for (int r2 = 0; r2 < 4; ++r2) {
                float v = acc[m][n][r2] + bv;
                if (g.outhalf) ((half_t*)g.C)[(size_t)(row0+r2)*g.ldc + col] = (half_t)v;
                else           ((float*)g.C)[(size_t)(row0+r2)*g.ldc + col] = v;
            }
        }
    }
}

// ---------------------------------------------------------------------------
__global__ __launch_bounds__(256) void transpose_wh_cvt(
    const float* __restrict__ wh1, const float* __restrict__ wh2,
    half_t* __restrict__ o1, half_t* __restrict__ o2)
{
    __shared__ float tile[64][65];
    const int z = blockIdx.z;
    const float* src = (z < 4 ? wh1 : wh2) + (size_t)(z & 3) * 1024 * 1024;
    half_t*      dst = (z < 4 ? o1  : o2 ) + (size_t)(z & 3) * 1024 * 1024;
    const int kb = blockIdx.x * 64, nb = blockIdx.y * 64;
    const int t = threadIdx.x;
    #pragma unroll
    for (int i = 0; i < 16; ++i) {
        int idx = t + i*256, r = idx >> 6, c = idx & 63;
        tile[r][c] = src[(size_t)(kb + r)*1024 + nb + c];
    }
    __syncthreads();
    #pragma unroll
    for (int i = 0; i < 16; ++i) {
        int idx = t + i*256, r = idx >> 6, c = idx & 63;
        dst[(size_t)(nb + r)*1024 + kb + c] = (half_t)tile[c][r];
    }
}

// fc1_w (fp32 [1024][512]) -> fc1t (fp16 [512][1024])  (transpose + convert)
__global__ __launch_bounds__(256) void transpose_fc1(
    const float* __restrict__ fc1_w, half_t* __restrict__ fc1t)
{
    __shared__ float tile[64][65];
    const int hb = blockIdx.x * 64, ob = blockIdx.y * 64;   // grid (16, 8)
    const int t = threadIdx.x;
    #pragma unroll
    for (int i = 0; i < 16; ++i) {
        int idx = t + i*256, r = idx >> 6, c = idx & 63;
        tile[r][c] = fc1_w[(size_t)(hb + r)*512 + ob + c];
    }
    __syncthreads();
    #pragma unroll
    for (int i = 0; i < 16; ++i) {
        int idx = t + i*256, r = idx >> 6, c = idx & 63;
        fc1t[(size_t)(ob + r)*1024 + hb + c] = (half_t)tile[c][r];
    }
}

// b1x[j] = b1[j] + dot(wx1[j,:], fc1_b)   (fp32, j < 4096; one block per j)
__global__ __launch_bounds__(256) void fold_b1(
    const float* __restrict__ wx1, const float* __restrict__ fc1_b,
    const float* __restrict__ b1, float* __restrict__ b1x)
{
    __shared__ float sred[4];
    const int j = blockIdx.x, t = threadIdx.x;
    float4 wv = *(const float4*)&wx1[(size_t)j*1024 + t*4];
    float4 bv = *(const float4*)&fc1_b[t*4];
    float s = wv.x*bv.x + wv.y*bv.y + wv.z*bv.z + wv.w*bv.w;
    float tot = block_sum(s, sred);
    if (t == 0) b1x[j] = b1[j] + tot;
}

__global__ __launch_bounds__(256) void cvt_f32_f16(
    const float* __restrict__ in, half_t* __restrict__ out, int n8)
{
    int i = blockIdx.x * 256 + threadIdx.x;
    if (i >= n8) return;
    float4 lo = ((const float4*)in)[2*i];
    float4 hi = ((const float4*)in)[2*i + 1];
    union { uint4 v; half_t h[8]; } r;
    r.h[0]=(half_t)lo.x; r.h[1]=(half_t)lo.y; r.h[2]=(half_t)lo.z; r.h[3]=(half_t)lo.w;
    r.h[4]=(half_t)hi.x; r.h[5]=(half_t)hi.y; r.h[6]=(half_t)hi.z; r.h[7]=(half_t)hi.w;
    ((uint4*)out)[i] = r.v;
}

extern "C" void kernel_launch(void* const* d_in, const int* in_sizes, int n_in,
                              void* d_out, int out_size, void* d_ws, size_t ws_size,
                              hipStream_t stream)
{
    const float* obs   = (const float*)d_in[0];
    const float* fc1_w = (const float*)d_in[1];
    const float* fc1_b = (const float*)d_in[2];
    const float* wx1   = (const float*)d_in[3];
    const float* wh1   = (const float*)d_in[4];
    const float* b1    = (const float*)d_in[5];
    const float* wx2   = (const float*)d_in[6];
    const float* wh2   = (const float*)d_in[7];
    const float* b2    = (const float*)d_in[8];
    const float* fc2_w = (const float*)d_in[9];
    const float* fc2_b = (const float*)d_in[10];
    float* out = (float*)d_out;

    char* ws = (char*)d_ws;
    size_t off = 0;
    auto carve = [&](size_t bytes) -> char* {
        char* p = ws + off; off += (bytes + 255) & ~(size_t)255; return p;
    };
    half_t* wx1c  = (half_t*)carve((size_t)4096*1024*2);    //  8.4 MB
    half_t* wh1t  = (half_t*)carve((size_t)4096*1024*2);
    half_t* wx2c  = (half_t*)carve((size_t)4096*1024*2);
    half_t* wh2t  = (half_t*)carve((size_t)4096*1024*2);
    half_t* fc1t  = (half_t*)carve((size_t)512*1024*2);     //  1.0 MB
    half_t* W1x   = (half_t*)carve((size_t)4096*512*2);     //  4.2 MB
    half_t* fc2c  = (half_t*)carve((size_t)1024*1024*2);
    float*  b1x   = (float*) carve((size_t)4096*4);
    half_t* preA1 = (half_t*)carve((size_t)512*4096*2);     //  4.2 MB
    half_t* preA2 = (half_t*)carve((size_t)512*4096*2);
    half_t* preB1 = (half_t*)carve((size_t)512*4096*2);
    half_t* preB2 = (half_t*)carve((size_t)512*4096*2);
    half_t* h0s   = (half_t*)carve((size_t)512*1024*2);
    half_t* h1s   = (half_t*)carve((size_t)512*1024*2);
    float*  c0    = (float*) carve((size_t)512*1024*4);
    float*  c1    = (float*) carve((size_t)512*1024*4);

    hipMemsetAsync(h1s, 0, (size_t)512*1024*2, stream);     // h1(-1)=0 for z1@st0
    hipMemsetAsync(c0,  0, (size_t)512*1024*4, stream);
    hipMemsetAsync(c1,  0, (size_t)512*1024*4, stream);
    hipMemsetAsync(preB1, 0, (size_t)512*4096*2, stream);   // h0(-1)=0

    // one-time conversions + fc1 fold
    cvt_f32_f16<<<2048, 256, 0, stream>>>(wx1,   wx1c,  4*1024*1024/8);
    cvt_f32_f16<<<2048, 256, 0, stream>>>(wx2,   wx2c,  4*1024*1024/8);
    cvt_f32_f16<<<512,  256, 0, stream>>>(fc2_w, fc2c,  1024*1024/8);
    transpose_wh_cvt<<<dim3(16,16,8), 256, 0, stream>>>(wh1, wh2, wh1t, wh2t);
    transpose_fc1<<<dim3(16,8), 256, 0, stream>>>(fc1_w, fc1t);
    fold_b1<<<4096, 256, 0, stream>>>(wx1, fc1_b, b1, b1x);

    GArgs Z{};
    auto ga = [](const half_t* A, int lda, const half_t* B, int ldb, int K,
                 const float* bias, void* C, int ldc, int outhalf) {
        GArgs g; g.A=A; g.B=B; g.bias=bias; g.C=C;
        g.lda=lda; g.ldb=ldb; g.K=K; g.ldc=ldc; g.outhalf=outhalf; return g;
    };

    // W1x[4096][512] = wx1c @ fc1t^T  (M=4096, N=512, K=1024; A large -> rowpin)
    gemm_ms<<<128, 256, 0, stream>>>(
        ga(wx1c, 1024, fc1t, 1024, 1024, nullptr, W1x, 512, 1), Z, Z, 32, 4, 1, 1);
    // preA1(0) = obs(0) @ W1x^T  (st=-1: z3-only pass of the step kernel)
    step_gemm4<<<512, 256, 0, stream>>>(
        obs, W1x, wx2c, wh1t, wh2t,
        preA1, preA2, preB1, preB2, h0s, h1s, -1);

    for (int st = 0; st < 64; ++st) {
        cells_kernel<<<1024, 256, 0, stream>>>(
            preA1, preB1, preA2, preB2, b1x, b2,
            c0, c1, h0s, h1s, out, st);
        step_gemm4<<<512, 256, 0, stream>>>(
            obs, W1x, wx2c, wh1t, wh2t,
            preA1, preA2, preB1, preB2, h0s, h1s, st);
    }
    cells_final<<<512, 256, 0, stream>>>(preA2, preB2, b2, c1, h1s, out);

    // fc2: logit = h1 @ fc2_w^T + fc2_b -> d_out[0 : 512*1024) fp32
    gemm_ms<<<4*8, 256, 0, stream>>>(
        ga(h1s, 1024, fc2c, 1024, 1024, fc2_b, out, 1024, 0), Z, Z, 4, 8, 1, 0);
}